// Round 1
// baseline (113.160 us; speedup 1.0000x reference)
//
#include <hip/hip_runtime.h>

// IAF inversion via incremental MADE recurrence.
// B=1024 rows, D=128 input dim, H=512 hidden, out = [z (B*D), log_det (B)].
//
// Per row (one 64-lane wave), lane l owns hidden units h = l + 64k, k in [0,8):
//   a[h] = b1[h] + sum_{i < d, i < m_hid[h]} W1[h,i] * z[i]   (running preact)
// Step d:
//   s_d = b2[d]   + sum_{h: m_hid[h] <= d} relu(a[h]) * W2[d,   h]
//   m_d = b2[D+d] + sum_{h: m_hid[h] <= d} relu(a[h]) * W2[D+d, h]
//   z_d = (x_d - m_d) * exp(-s_d);  log_det -= s_d
//   a[h] += W1[h,d] * z_d   for h with m_hid[h] > d
// Exactly equivalent to the reference scan (zeros in unfilled z contribute 0).

#define Bz  1024
#define Dd  128
#define Hh  512
#define HPL 8   // hidden units per lane = H / 64

__global__ void w1_transpose_kernel(const float* __restrict__ W1,
                                    float* __restrict__ W1T) {
    int idx = blockIdx.x * blockDim.x + threadIdx.x;  // 0 .. D*H-1
    if (idx < Dd * Hh) {
        int d = idx >> 9;    // idx / H
        int h = idx & 511;   // idx % H
        W1T[idx] = W1[h * Dd + d];   // W1T[d][h] = W1[h][d]
    }
}

__global__ __launch_bounds__(256) void iaf_kernel(
    const float* __restrict__ x,    // [B][D]
    const float* __restrict__ W1,   // [H][D]
    const float* __restrict__ b1,   // [H]
    const float* __restrict__ W2,   // [2D][H]
    const float* __restrict__ b2,   // [2D]
    const float* __restrict__ W1T,  // [D][H] (transposed), may be unused
    float* __restrict__ out,        // [B*D + B]
    int useT)
{
    const int lane = threadIdx.x & 63;
    const int wave = threadIdx.x >> 6;      // 4 waves per block
    const int row  = blockIdx.x * 4 + wave; // one row per wave

    float a[HPL];
    int   mhid[HPL];
#pragma unroll
    for (int k = 0; k < HPL; ++k) {
        int h   = lane + 64 * k;
        a[k]    = b1[h];
        mhid[k] = (h % 127) + 1;   // m_hid[h] = h % (D-1) + 1
    }

    const float* xr = x + row * Dd;
    float z0 = 0.f, z1 = 0.f, ld = 0.f;

    for (int d = 0; d < Dd; ++d) {
        // --- coalesced weight loads for this step (independent of z) ---
        float w2s[HPL], w2m[HPL], w1c[HPL];
#pragma unroll
        for (int k = 0; k < HPL; ++k) {
            int h  = lane + 64 * k;
            w2s[k] = W2[d * Hh + h];
            w2m[k] = W2[(Dd + d) * Hh + h];
            w1c[k] = useT ? W1T[d * Hh + h] : W1[h * Dd + d];
        }

        // --- masked dual dot-product over this lane's 8 hidden units ---
        float ps = 0.f, pm = 0.f;
#pragma unroll
        for (int k = 0; k < HPL; ++k) {
            float hv = fmaxf(a[k], 0.f);
            hv = (mhid[k] <= d) ? hv : 0.f;   // M2 row-d mask
            ps = fmaf(hv, w2s[k], ps);
            pm = fmaf(hv, w2m[k], pm);
        }

        // --- 64-lane butterfly reduce: every lane ends with full sums ---
#pragma unroll
        for (int off = 32; off > 0; off >>= 1) {
            ps += __shfl_xor(ps, off, 64);
            pm += __shfl_xor(pm, off, 64);
        }

        float s_d = ps + b2[d];
        float m_d = pm + b2[Dd + d];
        float zd  = (xr[d] - m_d) * __expf(-s_d);
        ld -= s_d;

        // stash z_d: lane (d%64) keeps it in a register
        if ((d & 63) == lane) { if (d < 64) z0 = zd; else z1 = zd; }

        // --- incremental preactivation update (M1 column-d mask) ---
#pragma unroll
        for (int k = 0; k < HPL; ++k)
            a[k] = (d < mhid[k]) ? fmaf(zd, w1c[k], a[k]) : a[k];
    }

    // coalesced output: z then log_det
    out[row * Dd + lane]      = z0;
    out[row * Dd + 64 + lane] = z1;
    if (lane == 0) out[Bz * Dd + row] = ld;
}

extern "C" void kernel_launch(void* const* d_in, const int* in_sizes, int n_in,
                              void* d_out, int out_size, void* d_ws, size_t ws_size,
                              hipStream_t stream) {
    const float* x  = (const float*)d_in[0];
    const float* W1 = (const float*)d_in[1];
    const float* b1 = (const float*)d_in[2];
    const float* W2 = (const float*)d_in[3];
    const float* b2 = (const float*)d_in[4];
    float* out = (float*)d_out;

    float* W1T = (float*)d_ws;
    int useT = (ws_size >= (size_t)(Dd * Hh * sizeof(float))) ? 1 : 0;
    if (useT) {
        w1_transpose_kernel<<<(Dd * Hh + 255) / 256, 256, 0, stream>>>(W1, W1T);
    }
    iaf_kernel<<<Bz / 4, 256, 0, stream>>>(x, W1, b1, W2, b2, W1T, out, useT);
}

// Round 2
// 105.690 us; speedup vs baseline: 1.0707x; 1.0707x over previous
//
#include <hip/hip_runtime.h>

// IAF inversion via incremental MADE recurrence — 2 rows per wave, software-
// pipelined weight prefetch, wave-uniform scalar loads for x/b2.
//
// Per row, lane l owns hidden units h = l + 64k, k in [0,8):
//   a[h] = b1[h] + sum_{i < d, i < m_hid[h]} W1[h,i] * z[i]
// Step d:
//   s_d = b2[d]     + sum_{h: m_hid[h] <= d} relu(a[h]) * W2[d,   h]
//   m_d = b2[D+d]   + sum_{h: m_hid[h] <= d} relu(a[h]) * W2[D+d, h]
//   z_d = (x_d - m_d) * exp(-s_d);  log_det -= s_d
//   a[h] += W1[h,d] * z_d   for m_hid[h] > d

#define Bz  1024
#define Dd  128
#define Hh  512
#define HPL 8   // hidden units per lane per row

__global__ void w1_transpose_kernel(const float* __restrict__ W1,
                                    float* __restrict__ W1T) {
    int idx = blockIdx.x * blockDim.x + threadIdx.x;
    if (idx < Dd * Hh) {
        int d = idx >> 9;
        int h = idx & 511;
        W1T[idx] = W1[h * Dd + d];
    }
}

__device__ __forceinline__ void load_w(const float* __restrict__ W2,
                                       const float* __restrict__ W1T,
                                       const float* __restrict__ W1,
                                       int useT, int lane, int dd,
                                       float (&w2s)[HPL], float (&w2m)[HPL],
                                       float (&w1c)[HPL]) {
#pragma unroll
    for (int k = 0; k < HPL; ++k) {
        int h  = lane + 64 * k;
        w2s[k] = W2[dd * Hh + h];
        w2m[k] = W2[(Dd + dd) * Hh + h];
        w1c[k] = useT ? W1T[dd * Hh + h] : W1[h * Dd + dd];
    }
}

__device__ __forceinline__ void stepfn(int d, int lane,
    float (&a0)[HPL], float (&a1)[HPL], const int (&mh)[HPL],
    const float (&w2s)[HPL], const float (&w2m)[HPL], const float (&w1c)[HPL],
    const float* __restrict__ x0, const float* __restrict__ x1,
    const float* __restrict__ b2,
    float &za0, float &zb0, float &za1, float &zb1, float &ld0, float &ld1)
{
    // dual masked dot for both rows (4 independent accumulator chains)
    float ps0 = 0.f, pm0 = 0.f, ps1 = 0.f, pm1 = 0.f;
#pragma unroll
    for (int k = 0; k < HPL; ++k) {
        bool on = (mh[k] <= d);
        float h0 = on ? fmaxf(a0[k], 0.f) : 0.f;
        float h1 = on ? fmaxf(a1[k], 0.f) : 0.f;
        ps0 = fmaf(h0, w2s[k], ps0);
        pm0 = fmaf(h0, w2m[k], pm0);
        ps1 = fmaf(h1, w2s[k], ps1);
        pm1 = fmaf(h1, w2m[k], pm1);
    }
    // 64-lane butterfly: 4 independent chains interleaved per level
#pragma unroll
    for (int off = 32; off > 0; off >>= 1) {
        ps0 += __shfl_xor(ps0, off, 64);
        pm0 += __shfl_xor(pm0, off, 64);
        ps1 += __shfl_xor(ps1, off, 64);
        pm1 += __shfl_xor(pm1, off, 64);
    }
    float bs = b2[d], bm = b2[Dd + d];          // wave-uniform (s_load)
    float s0 = ps0 + bs, m0 = pm0 + bm;
    float s1 = ps1 + bs, m1 = pm1 + bm;
    float zd0 = (x0[d] - m0) * __expf(-s0);     // x0[d]/x1[d] wave-uniform
    float zd1 = (x1[d] - m1) * __expf(-s1);
    ld0 -= s0;
    ld1 -= s1;
    if ((d & 63) == lane) {
        if (d < 64) { za0 = zd0; za1 = zd1; }
        else        { zb0 = zd0; zb1 = zd1; }
    }
    // incremental preactivation update (mask is complement of dot mask)
#pragma unroll
    for (int k = 0; k < HPL; ++k) {
        if (d < mh[k]) {
            a0[k] = fmaf(zd0, w1c[k], a0[k]);
            a1[k] = fmaf(zd1, w1c[k], a1[k]);
        }
    }
}

__global__ __launch_bounds__(64) void iaf2_kernel(
    const float* __restrict__ x,    // [B][D]
    const float* __restrict__ W1,   // [H][D]
    const float* __restrict__ b1,   // [H]
    const float* __restrict__ W2,   // [2D][H]
    const float* __restrict__ b2,   // [2D]
    const float* __restrict__ W1T,  // [D][H]
    float* __restrict__ out,        // [B*D + B]
    int useT)
{
    const int lane = threadIdx.x;        // blockDim = 64: one wave per block
    const int r0   = blockIdx.x * 2;     // two rows per wave
    const int r1   = r0 + 1;

    float a0[HPL], a1[HPL];
    int   mh[HPL];
#pragma unroll
    for (int k = 0; k < HPL; ++k) {
        int h = lane + 64 * k;
        float b = b1[h];
        a0[k] = b;
        a1[k] = b;
        mh[k] = (h % 127) + 1;
    }

    const float* x0 = x + r0 * Dd;
    const float* x1 = x + r1 * Dd;
    float za0 = 0.f, zb0 = 0.f, za1 = 0.f, zb1 = 0.f;
    float ld0 = 0.f, ld1 = 0.f;

    // double-buffered weight registers (ping-pong, statically indexed)
    float Aw2s[HPL], Aw2m[HPL], Aw1c[HPL];
    float Bw2s[HPL], Bw2m[HPL], Bw1c[HPL];
    load_w(W2, W1T, W1, useT, lane, 0, Aw2s, Aw2m, Aw1c);

    for (int d = 0; d < Dd; d += 2) {
        // prefetch d+1 while computing d
        load_w(W2, W1T, W1, useT, lane, d + 1, Bw2s, Bw2m, Bw1c);
        stepfn(d, lane, a0, a1, mh, Aw2s, Aw2m, Aw1c, x0, x1, b2,
               za0, zb0, za1, zb1, ld0, ld1);
        // prefetch d+2 (clamped: harmless redundant load on last iter)
        int dn = (d + 2 < Dd) ? d + 2 : Dd - 1;
        load_w(W2, W1T, W1, useT, lane, dn, Aw2s, Aw2m, Aw1c);
        stepfn(d + 1, lane, a0, a1, mh, Bw2s, Bw2m, Bw1c, x0, x1, b2,
               za0, zb0, za1, zb1, ld0, ld1);
    }

    // coalesced output: z rows then log_det
    out[r0 * Dd + lane]      = za0;
    out[r0 * Dd + 64 + lane] = zb0;
    out[r1 * Dd + lane]      = za1;
    out[r1 * Dd + 64 + lane] = zb1;
    if (lane == 0) {
        out[Bz * Dd + r0] = ld0;
        out[Bz * Dd + r1] = ld1;
    }
}

extern "C" void kernel_launch(void* const* d_in, const int* in_sizes, int n_in,
                              void* d_out, int out_size, void* d_ws, size_t ws_size,
                              hipStream_t stream) {
    const float* x  = (const float*)d_in[0];
    const float* W1 = (const float*)d_in[1];
    const float* b1 = (const float*)d_in[2];
    const float* W2 = (const float*)d_in[3];
    const float* b2 = (const float*)d_in[4];
    float* out = (float*)d_out;

    float* W1T = (float*)d_ws;
    int useT = (ws_size >= (size_t)(Dd * Hh * sizeof(float))) ? 1 : 0;
    if (useT) {
        w1_transpose_kernel<<<(Dd * Hh + 255) / 256, 256, 0, stream>>>(W1, W1T);
    }
    iaf2_kernel<<<Bz / 2, 64, 0, stream>>>(x, W1, b1, W2, b2, W1T, out, useT);
}

// Round 3
// 49.348 us; speedup vs baseline: 2.2931x; 2.1417x over previous
//
#include <hip/hip_runtime.h>

// IAF inversion via incremental MADE recurrence.
// 1 row per wave (1024 waves = 1/SIMD). Lane l owns hidden units
// h = l*8 + k, k in [0,8). Masks folded into pre-packed weights.
// Wave reduction via DPP (row_shr + row_bcast), not ds_bpermute.
//
//   a[h] = b1[h] + sum_{i<d, i<m_hid[h]} W1[h,i] z[i]
//   s_d  = b2[d]   + sum_h relu(a[h]) * W2s_masked[d,h]
//   m_d  = b2[D+d] + sum_h relu(a[h]) * W2m_masked[d,h]
//   z_d  = (x_d - m_d) * exp(-s_d);  log_det -= s_d
//   a[h] += W1_masked[d,h] * z_d

#define Bz  1024
#define Dd  128
#define Hh  512
#define HPL 8

// ---------- DPP wave-64 sum, result broadcast via readlane ----------
template<int CTRL, int RMASK>
__device__ __forceinline__ float dpp_add(float v) {
    int t = __builtin_amdgcn_update_dpp(0, __float_as_int(v), CTRL, RMASK, 0xf, true);
    return v + __int_as_float(t);
}
__device__ __forceinline__ float wave_sum_bcast(float v) {
    v = dpp_add<0x111, 0xf>(v);  // row_shr:1
    v = dpp_add<0x112, 0xf>(v);  // row_shr:2
    v = dpp_add<0x114, 0xf>(v);  // row_shr:4
    v = dpp_add<0x118, 0xf>(v);  // row_shr:8  -> lane15 of each row16 has row sum
    v = dpp_add<0x142, 0xa>(v);  // row_bcast:15 into rows 1,3
    v = dpp_add<0x143, 0xc>(v);  // row_bcast:31 into rows 2,3 -> lane63 = total
    return __int_as_float(__builtin_amdgcn_readlane(__float_as_int(v), 63));
}
__device__ __forceinline__ float bcast_lane(float v, int l) {
    return __int_as_float(__builtin_amdgcn_readlane(__float_as_int(v), l));
}

// ---------- pre-pack: masked weights, per-step contiguous ----------
// Wp[d*1536 + 0..511]    = W2[d,     h] * (m_hid[h] <= d)
// Wp[d*1536 + 512..1023] = W2[D+d,   h] * (m_hid[h] <= d)
// Wp[d*1536 + 1024..1535]= W1[h, d]     * (m_hid[h] >  d)
__global__ void pack_kernel(const float* __restrict__ W1,
                            const float* __restrict__ W2,
                            float* __restrict__ Wp) {
    int idx = blockIdx.x * blockDim.x + threadIdx.x;
    if (idx >= Dd * Hh) return;
    int d = idx >> 9, h = idx & 511;
    int mh = (h % 127) + 1;
    float dot_on = (mh <= d) ? 1.f : 0.f;
    float upd_on = (mh >  d) ? 1.f : 0.f;
    float* bp = Wp + d * 1536;
    bp[h]        = W2[d * Hh + h] * dot_on;
    bp[512 + h]  = W2[(Dd + d) * Hh + h] * dot_on;
    bp[1024 + h] = W1[h * Dd + d] * upd_on;
}

__global__ void w1t_kernel(const float* __restrict__ W1, float* __restrict__ W1T) {
    int idx = blockIdx.x * blockDim.x + threadIdx.x;
    if (idx < Dd * Hh) {
        int d = idx >> 9, h = idx & 511;
        W1T[idx] = W1[h * Dd + d];
    }
}

// ---------- per-step weight load (6x dwordx4 in MODE 2) ----------
template<int MODE>
__device__ __forceinline__ void load_w(const float* __restrict__ W1,
                                       const float* __restrict__ W2,
                                       const float* __restrict__ Wp,
                                       int dd, int h0,
                                       float (&S)[HPL], float (&M)[HPL], float (&Wv)[HPL]) {
    if (MODE == 2) {
        const float* b = Wp + dd * 1536 + h0;
        float4 t0 = *(const float4*)(b);
        float4 t1 = *(const float4*)(b + 4);
        float4 t2 = *(const float4*)(b + 512);
        float4 t3 = *(const float4*)(b + 516);
        float4 t4 = *(const float4*)(b + 1024);
        float4 t5 = *(const float4*)(b + 1028);
        S[0]=t0.x; S[1]=t0.y; S[2]=t0.z; S[3]=t0.w; S[4]=t1.x; S[5]=t1.y; S[6]=t1.z; S[7]=t1.w;
        M[0]=t2.x; M[1]=t2.y; M[2]=t2.z; M[3]=t2.w; M[4]=t3.x; M[5]=t3.y; M[6]=t3.z; M[7]=t3.w;
        Wv[0]=t4.x;Wv[1]=t4.y;Wv[2]=t4.z;Wv[3]=t4.w;Wv[4]=t5.x;Wv[5]=t5.y;Wv[6]=t5.z;Wv[7]=t5.w;
    } else {
        const float* bs = W2 + dd * Hh + h0;
        const float* bm = W2 + (Dd + dd) * Hh + h0;
        float4 t0 = *(const float4*)(bs);
        float4 t1 = *(const float4*)(bs + 4);
        float4 t2 = *(const float4*)(bm);
        float4 t3 = *(const float4*)(bm + 4);
        S[0]=t0.x; S[1]=t0.y; S[2]=t0.z; S[3]=t0.w; S[4]=t1.x; S[5]=t1.y; S[6]=t1.z; S[7]=t1.w;
        M[0]=t2.x; M[1]=t2.y; M[2]=t2.z; M[3]=t2.w; M[4]=t3.x; M[5]=t3.y; M[6]=t3.z; M[7]=t3.w;
        if (MODE == 1) {
            const float* bw = Wp + dd * Hh + h0;
            float4 t4 = *(const float4*)(bw);
            float4 t5 = *(const float4*)(bw + 4);
            Wv[0]=t4.x;Wv[1]=t4.y;Wv[2]=t4.z;Wv[3]=t4.w;Wv[4]=t5.x;Wv[5]=t5.y;Wv[6]=t5.z;Wv[7]=t5.w;
        } else {
#pragma unroll
            for (int k = 0; k < HPL; ++k) Wv[k] = W1[(h0 + k) * Dd + dd];
        }
    }
}

template<int MODE>
__device__ __forceinline__ void stepfn(int d, int lane,
    float (&a)[HPL], const int (&mh)[HPL],
    const float (&S)[HPL], const float (&M)[HPL], const float (&Wv)[HPL],
    float xa, float xb, float b2a, float b2b, float b2c, float b2dd,
    float &za, float &zb, float &ld)
{
    // masked dual dot, 4 accumulator chains for dep-depth 4+1
    float ps0 = 0.f, ps1 = 0.f, pm0 = 0.f, pm1 = 0.f;
#pragma unroll
    for (int k = 0; k < HPL; ++k) {
        float h = fmaxf(a[k], 0.f);
        if (MODE < 2) h = (mh[k] <= d) ? h : 0.f;
        if (k & 1) { ps1 = fmaf(h, S[k], ps1); pm1 = fmaf(h, M[k], pm1); }
        else       { ps0 = fmaf(h, S[k], ps0); pm0 = fmaf(h, M[k], pm0); }
    }
    float ps = wave_sum_bcast(ps0 + ps1);
    float pm = wave_sum_bcast(pm0 + pm1);

    int dl = d & 63;
    float sd = ps + bcast_lane(d < 64 ? b2a : b2b, dl);
    float md = pm + bcast_lane(d < 64 ? b2c : b2dd, dl);
    float xv =      bcast_lane(d < 64 ? xa  : xb,  dl);
    float zd = (xv - md) * __expf(-sd);
    ld -= sd;
    if (dl == lane) { if (d < 64) za = zd; else zb = zd; }

#pragma unroll
    for (int k = 0; k < HPL; ++k) {
        if (MODE == 2) a[k] = fmaf(zd, Wv[k], a[k]);           // mask pre-folded
        else           a[k] = (d < mh[k]) ? fmaf(zd, Wv[k], a[k]) : a[k];
    }
}

template<int MODE>
__global__ __launch_bounds__(64) void iaf_kernel(
    const float* __restrict__ x,
    const float* __restrict__ W1,
    const float* __restrict__ b1,
    const float* __restrict__ W2,
    const float* __restrict__ b2,
    const float* __restrict__ Wp,
    float* __restrict__ out)
{
    const int lane = (int)threadIdx.x;     // one wave per block
    const int row  = (int)blockIdx.x;      // one row per wave
    const int h0   = lane * HPL;           // lane owns h0..h0+7

    float a[HPL];
    {
        float4 t0 = *(const float4*)(b1 + h0);
        float4 t1 = *(const float4*)(b1 + h0 + 4);
        a[0]=t0.x; a[1]=t0.y; a[2]=t0.z; a[3]=t0.w;
        a[4]=t1.x; a[5]=t1.y; a[6]=t1.z; a[7]=t1.w;
    }
    int mh[HPL];
#pragma unroll
    for (int k = 0; k < HPL; ++k) mh[k] = ((h0 + k) % 127) + 1;  // DCE'd in MODE 2

    // preload x row and b2 into lane-distributed registers
    float xa  = x[row * Dd + lane];
    float xb  = x[row * Dd + 64 + lane];
    float b2a = b2[lane], b2b = b2[64 + lane], b2c = b2[128 + lane], b2dd = b2[192 + lane];

    float za = 0.f, zb = 0.f, ld = 0.f;

    float cs[HPL], cm[HPL], cw[HPL];   // current-step weights
    float ns[HPL], nm[HPL], nw[HPL];   // next-step weights
    load_w<MODE>(W1, W2, Wp, 0, h0, cs, cm, cw);

#pragma unroll 1
    for (int d = 0; d < Dd; d += 2) {
        load_w<MODE>(W1, W2, Wp, d + 1, h0, ns, nm, nw);   // prefetch d+1
        __builtin_amdgcn_sched_barrier(0);                 // pin loads above compute
        stepfn<MODE>(d, lane, a, mh, cs, cm, cw, xa, xb, b2a, b2b, b2c, b2dd, za, zb, ld);
        int dn = (d + 2 < Dd) ? d + 2 : Dd - 1;
        load_w<MODE>(W1, W2, Wp, dn, h0, cs, cm, cw);      // prefetch d+2
        __builtin_amdgcn_sched_barrier(0);
        stepfn<MODE>(d + 1, lane, a, mh, ns, nm, nw, xa, xb, b2a, b2b, b2c, b2dd, za, zb, ld);
    }

    out[row * Dd + lane]      = za;
    out[row * Dd + 64 + lane] = zb;
    if (lane == 0) out[Bz * Dd + row] = ld;
}

extern "C" void kernel_launch(void* const* d_in, const int* in_sizes, int n_in,
                              void* d_out, int out_size, void* d_ws, size_t ws_size,
                              hipStream_t stream) {
    const float* x  = (const float*)d_in[0];
    const float* W1 = (const float*)d_in[1];
    const float* b1 = (const float*)d_in[2];
    const float* W2 = (const float*)d_in[3];
    const float* b2 = (const float*)d_in[4];
    float* out = (float*)d_out;
    float* Wp  = (float*)d_ws;

    const size_t need2 = (size_t)Dd * 1536 * sizeof(float);  // 768 KB packed
    const size_t need1 = (size_t)Dd * Hh * sizeof(float);    // 256 KB W1T

    if (ws_size >= need2) {
        pack_kernel<<<(Dd * Hh + 255) / 256, 256, 0, stream>>>(W1, W2, Wp);
        iaf_kernel<2><<<Bz, 64, 0, stream>>>(x, W1, b1, W2, b2, Wp, out);
    } else if (ws_size >= need1) {
        w1t_kernel<<<(Dd * Hh + 255) / 256, 256, 0, stream>>>(W1, Wp);
        iaf_kernel<1><<<Bz, 64, 0, stream>>>(x, W1, b1, W2, b2, Wp, out);
    } else {
        iaf_kernel<0><<<Bz, 64, 0, stream>>>(x, W1, b1, W2, b2, Wp, out);
    }
}

// Round 5
// 38.722 us; speedup vs baseline: 2.9223x; 1.2744x over previous
//
#include <hip/hip_runtime.h>

// IAF inversion via incremental MADE recurrence.
// 1 row per wave, 1024 single-wave blocks = 1 wave/SIMD chip-wide.
// Masks folded into packed weights Wp (768 KB in d_ws, L2-resident).
// __launch_bounds__(64,1): tell RA occupancy=1 is fine -> quad-buffered
// register prefetch stays RESIDENT (R2 failed at 40 VGPRs: loads were
// rematerialized at uses, putting ~200cyc L2 latency on the serial chain).
// Wave reduction via DPP row_shr/row_bcast + readlane (no LDS, no barriers).

#define Bz  1024
#define Dd  128
#define Hh  512
#define HPL 8

typedef float v4f __attribute__((ext_vector_type(4)));

// ---------------- DPP wave-64 sum ----------------
template<int CTRL, int RMASK>
__device__ __forceinline__ float dpp_add(float v) {
    int t = __builtin_amdgcn_update_dpp(0, __float_as_int(v), CTRL, RMASK, 0xf, true);
    return v + __int_as_float(t);
}
__device__ __forceinline__ float wave_sum_bcast(float v) {
    v = dpp_add<0x111, 0xf>(v);  // row_shr:1
    v = dpp_add<0x112, 0xf>(v);  // row_shr:2
    v = dpp_add<0x114, 0xf>(v);  // row_shr:4
    v = dpp_add<0x118, 0xf>(v);  // row_shr:8
    v = dpp_add<0x142, 0xa>(v);  // row_bcast:15
    v = dpp_add<0x143, 0xc>(v);  // row_bcast:31 -> lane63 = total
    return __int_as_float(__builtin_amdgcn_readlane(__float_as_int(v), 63));
}
__device__ __forceinline__ float bcast_lane(float v, int l) {
    return __int_as_float(__builtin_amdgcn_readlane(__float_as_int(v), l));
}

// ---------------- pre-pack masked weights ----------------
// Wp[d*1536 + 0..511]     = W2[d,h]   * (m_hid[h] <= d)
// Wp[d*1536 + 512..1023]  = W2[D+d,h] * (m_hid[h] <= d)
// Wp[d*1536 + 1024..1535] = W1[h,d]   * (m_hid[h] >  d)
__global__ void pack_kernel(const float* __restrict__ W1,
                            const float* __restrict__ W2,
                            float* __restrict__ Wp) {
    int idx = blockIdx.x * blockDim.x + threadIdx.x;
    if (idx >= Dd * Hh) return;
    int d = idx >> 9, h = idx & 511;
    int mh = (h % 127) + 1;
    float dot_on = (mh <= d) ? 1.f : 0.f;
    float upd_on = (mh >  d) ? 1.f : 0.f;
    float* bp = Wp + d * 1536;
    bp[h]        = W2[d * Hh + h] * dot_on;
    bp[512 + h]  = W2[(Dd + d) * Hh + h] * dot_on;
    bp[1024 + h] = W1[h * Dd + d] * upd_on;
}

// ---------------- weight buffer (24 VGPRs each) ----------------
struct WBuf { v4f s0, s1, m0, m1, w0, w1; };

__device__ __forceinline__ void loadbuf(WBuf &b, const float* p) {
    b.s0 = *(const v4f*)(p);          // W2-sigma (masked)
    b.s1 = *(const v4f*)(p + 4);
    b.m0 = *(const v4f*)(p + 512);    // W2-mu (masked)
    b.m1 = *(const v4f*)(p + 516);
    b.w0 = *(const v4f*)(p + 1024);   // W1 column (masked)
    b.w1 = *(const v4f*)(p + 1028);
    __builtin_amdgcn_sched_barrier(0);  // pin: don't sink these loads
}

// ---------------- one recurrence step ----------------
__device__ __forceinline__ void stepD(int d, int lane,
    float (&a)[HPL], const WBuf &w,
    float xa, float xb, float b2a, float b2b, float b2c, float b2d_,
    float &za, float &zb, float &ld)
{
    float ps0 = 0.f, ps1 = 0.f, pm0 = 0.f, pm1 = 0.f;
#pragma unroll
    for (int k = 0; k < 4; ++k) {
        float h = fmaxf(a[k], 0.f);
        ps0 = fmaf(h, w.s0[k], ps0);
        pm0 = fmaf(h, w.m0[k], pm0);
    }
#pragma unroll
    for (int k = 0; k < 4; ++k) {
        float h = fmaxf(a[4 + k], 0.f);
        ps1 = fmaf(h, w.s1[k], ps1);
        pm1 = fmaf(h, w.m1[k], pm1);
    }
    float ps = wave_sum_bcast(ps0 + ps1);
    float pm = wave_sum_bcast(pm0 + pm1);

    int dl = d & 63;
    float sd = ps + bcast_lane(d < 64 ? b2a : b2b, dl);
    float md = pm + bcast_lane(d < 64 ? b2c : b2d_, dl);
    float xv =      bcast_lane(d < 64 ? xa  : xb,  dl);
    float zd = (xv - md) * __expf(-sd);
    ld -= sd;
    if (dl == lane) { if (d < 64) za = zd; else zb = zd; }

#pragma unroll
    for (int k = 0; k < 4; ++k) a[k]     = fmaf(zd, w.w0[k], a[k]);
#pragma unroll
    for (int k = 0; k < 4; ++k) a[4 + k] = fmaf(zd, w.w1[k], a[4 + k]);
}

__global__ __launch_bounds__(64, 1) void iaf4_kernel(
    const float* __restrict__ x,
    const float* __restrict__ b1,
    const float* __restrict__ b2,
    const float* __restrict__ Wp,
    float* __restrict__ out)
{
    const int lane = (int)threadIdx.x;
    const int row  = (int)blockIdx.x;
    const int h0   = lane * HPL;

    float a[HPL];
    {
        float4 t0 = *(const float4*)(b1 + h0);
        float4 t1 = *(const float4*)(b1 + h0 + 4);
        a[0]=t0.x; a[1]=t0.y; a[2]=t0.z; a[3]=t0.w;
        a[4]=t1.x; a[5]=t1.y; a[6]=t1.z; a[7]=t1.w;
    }
    float xa  = x[row * Dd + lane];
    float xb  = x[row * Dd + 64 + lane];
    float b2a = b2[lane],       b2b = b2[64 + lane];
    float b2c = b2[128 + lane], b2d_ = b2[192 + lane];

    float za = 0.f, zb = 0.f, ld = 0.f;

    const float* base = Wp + h0;
    WBuf A, B, C, D;
    loadbuf(A, base + 0 * 1536);
    loadbuf(B, base + 1 * 1536);
    loadbuf(C, base + 2 * 1536);
    loadbuf(D, base + 3 * 1536);

#pragma unroll 1
    for (int t = 0; t < Dd; t += 4) {
        stepD(t + 0, lane, a, A, xa, xb, b2a, b2b, b2c, b2d_, za, zb, ld);
        loadbuf(A, base + (size_t)((t + 4 < Dd) ? (t + 4) : 0) * 1536);
        stepD(t + 1, lane, a, B, xa, xb, b2a, b2b, b2c, b2d_, za, zb, ld);
        loadbuf(B, base + (size_t)((t + 5 < Dd) ? (t + 5) : 1) * 1536);
        stepD(t + 2, lane, a, C, xa, xb, b2a, b2b, b2c, b2d_, za, zb, ld);
        loadbuf(C, base + (size_t)((t + 6 < Dd) ? (t + 6) : 2) * 1536);
        stepD(t + 3, lane, a, D, xa, xb, b2a, b2b, b2c, b2d_, za, zb, ld);
        loadbuf(D, base + (size_t)((t + 7 < Dd) ? (t + 7) : 3) * 1536);
    }

    out[row * Dd + lane]      = za;
    out[row * Dd + 64 + lane] = zb;
    if (lane == 0) out[Bz * Dd + row] = ld;
}

// ---------------- fallback (ws too small): masked direct loads ----------------
__global__ __launch_bounds__(64, 1) void iaf_fb_kernel(
    const float* __restrict__ x,  const float* __restrict__ W1,
    const float* __restrict__ b1, const float* __restrict__ W2,
    const float* __restrict__ b2, float* __restrict__ out)
{
    const int lane = (int)threadIdx.x;
    const int row  = (int)blockIdx.x;
    const int h0   = lane * HPL;
    float a[HPL]; int mh[HPL];
#pragma unroll
    for (int k = 0; k < HPL; ++k) { a[k] = b1[h0 + k]; mh[k] = ((h0 + k) % 127) + 1; }
    float xa  = x[row * Dd + lane], xb = x[row * Dd + 64 + lane];
    float b2a = b2[lane], b2b = b2[64 + lane], b2c = b2[128 + lane], b2d_ = b2[192 + lane];
    float za = 0.f, zb = 0.f, ld = 0.f;
    for (int d = 0; d < Dd; ++d) {
        float ps = 0.f, pm = 0.f;
#pragma unroll
        for (int k = 0; k < HPL; ++k) {
            float h = fmaxf(a[k], 0.f);
            h = (mh[k] <= d) ? h : 0.f;
            ps = fmaf(h, W2[d * Hh + h0 + k], ps);
            pm = fmaf(h, W2[(Dd + d) * Hh + h0 + k], pm);
        }
        ps = wave_sum_bcast(ps);
        pm = wave_sum_bcast(pm);
        int dl = d & 63;
        float sd = ps + bcast_lane(d < 64 ? b2a : b2b, dl);
        float md = pm + bcast_lane(d < 64 ? b2c : b2d_, dl);
        float xv =      bcast_lane(d < 64 ? xa  : xb,  dl);
        float zd = (xv - md) * __expf(-sd);
        ld -= sd;
        if (dl == lane) { if (d < 64) za = zd; else zb = zd; }
#pragma unroll
        for (int k = 0; k < HPL; ++k)
            if (d < mh[k]) a[k] = fmaf(zd, W1[(h0 + k) * Dd + d], a[k]);
    }
    out[row * Dd + lane]      = za;
    out[row * Dd + 64 + lane] = zb;
    if (lane == 0) out[Bz * Dd + row] = ld;
}

extern "C" void kernel_launch(void* const* d_in, const int* in_sizes, int n_in,
                              void* d_out, int out_size, void* d_ws, size_t ws_size,
                              hipStream_t stream) {
    const float* x  = (const float*)d_in[0];
    const float* W1 = (const float*)d_in[1];
    const float* b1 = (const float*)d_in[2];
    const float* W2 = (const float*)d_in[3];
    const float* b2 = (const float*)d_in[4];
    float* out = (float*)d_out;
    float* Wp  = (float*)d_ws;

    const size_t need = (size_t)Dd * 1536 * sizeof(float);  // 768 KB
    if (ws_size >= need) {
        pack_kernel<<<(Dd * Hh + 255) / 256, 256, 0, stream>>>(W1, W2, Wp);
        iaf4_kernel<<<Bz, 64, 0, stream>>>(x, b1, b2, Wp, out);
    } else {
        iaf_fb_kernel<<<Bz, 64, 0, stream>>>(x, W1, b1, W2, b2, out);
    }
}